// Round 1
// baseline (3570.890 us; speedup 1.0000x reference)
//
#include <hip/hip_runtime.h>
#include <math.h>

// Problem constants
#define D_MODEL 2048
#define NHEADS  16
#define HD      128
#define SEQ     2048
#define BATCH   2
#define MROWS   (BATCH*SEQ)            // 4096 rows for the projection GEMMs
#define BHS_ROWS (BATCH*NHEADS*SEQ)    // 65536 rows per Q/K/V buffer
#define QKV_ELEMS (BATCH*NHEADS*SEQ*HD) // 8388608 floats per buffer

// ---------------------------------------------------------------------------
// GEMM: C[m][n] = sum_k A[m][k] * W[n][k] + bias[n]   (A: MxK, W: NxK, both
// row-major, k contiguous -> "NT" gemm, both tiles load coalesced along k)
// Tile 128x128, BK=16, 256 threads, 8x8 accumulators per thread.
// MODE 0: blockIdx.z selects (Wq,bq,Q)/(Wk,bk,K)/(Wv,bv,V); output written to
//         [B,H,S,HD] layout (BN=128==HD so each block maps to exactly 1 head).
// MODE 1: plain row-major [M,N] output (final projection into d_out).
// ---------------------------------------------------------------------------
template<int MODE>
__global__ __launch_bounds__(256)
void gemm_nt(const float* __restrict__ A,
             const float* __restrict__ W0, const float* __restrict__ W1, const float* __restrict__ W2,
             const float* __restrict__ b0_, const float* __restrict__ b1_, const float* __restrict__ b2_,
             float* __restrict__ out0, float* __restrict__ out1, float* __restrict__ out2)
{
    const int K = 2048, N = 2048;
    const float* W = W0; const float* bias = b0_; float* dst = out0;
    if (MODE == 0) {
        if (blockIdx.z == 1) { W = W1; bias = b1_; dst = out1; }
        else if (blockIdx.z == 2) { W = W2; bias = b2_; dst = out2; }
    }

    // pad 132: row stride 528B (16B-aligned for b128), 132%32==4 -> hot reads 2-way max (free)
    __shared__ __align__(16) float As[16][132];
    __shared__ __align__(16) float Bs[16][132];

    const int t  = threadIdx.x;
    const int m0 = blockIdx.y * 128, n0 = blockIdx.x * 128;
    const int tn = t & 15, tm = t >> 4;

    float acc[8][8];
#pragma unroll
    for (int i = 0; i < 8; i++)
#pragma unroll
        for (int j = 0; j < 8; j++) acc[i][j] = 0.f;

    const int row0 = t >> 2;        // 0..63  (A/B tile rows, iter 0)
    const int seg  = t & 3;         // float4 segment within 16-wide k

    for (int kt = 0; kt < K; kt += 16) {
        // global -> regs (coalesced 64B per 4 lanes)
        float4 a0 = *(const float4*)(A + (size_t)(m0 + row0     ) * K + kt + seg * 4);
        float4 a1 = *(const float4*)(A + (size_t)(m0 + row0 + 64) * K + kt + seg * 4);
        float4 b0 = *(const float4*)(W + (size_t)(n0 + row0     ) * K + kt + seg * 4);
        float4 b1 = *(const float4*)(W + (size_t)(n0 + row0 + 64) * K + kt + seg * 4);
        __syncthreads();            // previous tile's compute done
        // transpose into [k][m] / [k][n]
        As[seg*4+0][row0] = a0.x; As[seg*4+1][row0] = a0.y; As[seg*4+2][row0] = a0.z; As[seg*4+3][row0] = a0.w;
        As[seg*4+0][row0+64] = a1.x; As[seg*4+1][row0+64] = a1.y; As[seg*4+2][row0+64] = a1.z; As[seg*4+3][row0+64] = a1.w;
        Bs[seg*4+0][row0] = b0.x; Bs[seg*4+1][row0] = b0.y; Bs[seg*4+2][row0] = b0.z; Bs[seg*4+3][row0] = b0.w;
        Bs[seg*4+0][row0+64] = b1.x; Bs[seg*4+1][row0+64] = b1.y; Bs[seg*4+2][row0+64] = b1.z; Bs[seg*4+3][row0+64] = b1.w;
        __syncthreads();

#pragma unroll
        for (int k = 0; k < 16; k++) {
            float4 av0 = *(const float4*)&As[k][tm*4];
            float4 av1 = *(const float4*)&As[k][64 + tm*4];
            float4 bv0 = *(const float4*)&Bs[k][tn*4];
            float4 bv1 = *(const float4*)&Bs[k][64 + tn*4];
            float a[8] = {av0.x, av0.y, av0.z, av0.w, av1.x, av1.y, av1.z, av1.w};
            float b[8] = {bv0.x, bv0.y, bv0.z, bv0.w, bv1.x, bv1.y, bv1.z, bv1.w};
#pragma unroll
            for (int i = 0; i < 8; i++)
#pragma unroll
                for (int j = 0; j < 8; j++) acc[i][j] += a[i] * b[j];
        }
    }

    // epilogue
    float bv_[8];
#pragma unroll
    for (int j = 0; j < 4; j++) { bv_[j] = bias[n0 + tn*4 + j]; bv_[j+4] = bias[n0 + 64 + tn*4 + j]; }

#pragma unroll
    for (int i = 0; i < 8; i++) {
        int rl = (i < 4) ? (tm*4 + i) : (64 + tm*4 + (i - 4));
        int m = m0 + rl;
        float4 w0 = { acc[i][0] + bv_[0], acc[i][1] + bv_[1], acc[i][2] + bv_[2], acc[i][3] + bv_[3] };
        float4 w1 = { acc[i][4] + bv_[4], acc[i][5] + bv_[5], acc[i][6] + bv_[6], acc[i][7] + bv_[7] };
        if (MODE == 1) {
            *(float4*)(dst + (size_t)m * N + n0 + tn*4) = w0;
            *(float4*)(dst + (size_t)m * N + n0 + 64 + tn*4) = w1;
        } else {
            int h = n0 >> 7;                   // BN==HD: one head per block column
            int b = m >> 11, s = m & (SEQ - 1);
            size_t base = ((size_t)(b * NHEADS + h) * SEQ + s) * HD;
            *(float4*)(dst + base + tn*4) = w0;
            *(float4*)(dst + base + 64 + tn*4) = w1;
        }
    }
}

// ---------------------------------------------------------------------------
// RoPE (the reference's quirky double-trig version), in-place on Q and K.
// emb = [sin(s*f), cos(s*f)]; q_rot = q*cos(emb) + rotate_half(q)*sin(emb)
//   d<64 : q[d]*cos(sin(sf)) - q[d+64]*sin(sin(sf))
//   d>=64: q[d]*cos(cos(sf)) + q[d-64]*sin(cos(sf))
// One wave-lane handles the (d, d+64) pair. 4 rows per 256-thread block.
// ---------------------------------------------------------------------------
__global__ __launch_bounds__(256)
void rope_kernel(float* __restrict__ Q, float* __restrict__ Kb)
{
    const int t = threadIdx.x;
    const int lane = t & 63, rsub = t >> 6;
    const long grow = (long)blockIdx.x * 4 + rsub;      // 0 .. 2*BHS_ROWS-1
    float* buf = (grow < BHS_ROWS) ? Q : Kb;
    const int row = (int)(grow & (BHS_ROWS - 1));
    const int s = row & (SEQ - 1);                      // layout [B,H,S,HD]
    float* p = buf + (size_t)row * HD;

    float a = p[lane];
    float c2 = p[lane + 64];
    // inv_freq = 10000^(-(2*lane)/128); use precise powf (fp32, ~1ulp)
    float f = powf(10000.0f, -(float)(2 * lane) / 128.0f);
    float sv = (float)s * f;
    float sn = sinf(sv), cs = cosf(sv);
    float ce1 = cosf(sn), se1 = sinf(sn);
    float ce2 = cosf(cs), se2 = sinf(cs);
    p[lane]      = a * ce1 - c2 * se1;
    p[lane + 64] = c2 * ce2 + a * se2;
}

// ---------------------------------------------------------------------------
// Flash attention, fp32. One block = one (b,h) x 32-query tile; K/V streamed
// in 32-row tiles through LDS with online softmax. No score materialization.
// Score phase: thread t -> rows {t&15, (t&15)+16} x cols {t>>4, (t>>4)+16}
// PV phase:    thread t -> rows (t&7)*4..+3, dims (t>>3)*4..+3
// ---------------------------------------------------------------------------
__global__ __launch_bounds__(256)
void flash_attn(const float* __restrict__ Q, const float* __restrict__ Kb,
                const float* __restrict__ Vb, float* __restrict__ O)
{
    const int t  = threadIdx.x;
    const int q0 = blockIdx.x * 32;
    const int bh = blockIdx.y;
    const int b = bh >> 4, h = bh & 15;
    const float SCALE = 0.08838834764831845f;   // 1/sqrt(128)

    __shared__ __align__(16) float Qs[32][132];
    __shared__ __align__(16) float Ks[32][132];
    __shared__ __align__(16) float Vs[32][132];
    __shared__ __align__(16) float Pt[32][36];  // scores transposed [kj][qi]
    __shared__ float m_s[32], l_s[32], al_s[32];

    // stage Q tile (32 x 128)
    const float* qbase = Q + ((size_t)bh * SEQ + q0) * HD;
#pragma unroll
    for (int r = 0; r < 4; r++) {
        int id = t + 256 * r;
        int row = id >> 5, sg = id & 31;
        *(float4*)&Qs[row][sg * 4] = *(const float4*)(qbase + (size_t)row * HD + sg * 4);
    }
    if (t < 32) { m_s[t] = -INFINITY; l_s[t] = 0.f; }

    float o[4][4];
#pragma unroll
    for (int i = 0; i < 4; i++)
#pragma unroll
        for (int j = 0; j < 4; j++) o[i][j] = 0.f;

    const int qi_s = t & 15, kj_s = t >> 4;   // score mapping
    const int qg = t & 7,   dc = t >> 3;      // PV mapping
    __syncthreads();

    for (int kt = 0; kt < SEQ; kt += 32) {
        const float* kbase = Kb + ((size_t)bh * SEQ + kt) * HD;
        const float* vbase = Vb + ((size_t)bh * SEQ + kt) * HD;
#pragma unroll
        for (int r = 0; r < 4; r++) {
            int id = t + 256 * r;
            int row = id >> 5, sg = id & 31;
            *(float4*)&Ks[row][sg * 4] = *(const float4*)(kbase + (size_t)row * HD + sg * 4);
            *(float4*)&Vs[row][sg * 4] = *(const float4*)(vbase + (size_t)row * HD + sg * 4);
        }
        __syncthreads();

        // ---- scores: 2x2 per thread over 128-dot
        float s00 = 0.f, s01 = 0.f, s10 = 0.f, s11 = 0.f;
#pragma unroll 4
        for (int d4 = 0; d4 < 32; d4++) {
            float4 qa = *(const float4*)&Qs[qi_s][d4 * 4];
            float4 qb = *(const float4*)&Qs[qi_s + 16][d4 * 4];
            float4 ka = *(const float4*)&Ks[kj_s][d4 * 4];
            float4 kb = *(const float4*)&Ks[kj_s + 16][d4 * 4];
            s00 += qa.x*ka.x + qa.y*ka.y + qa.z*ka.z + qa.w*ka.w;
            s01 += qa.x*kb.x + qa.y*kb.y + qa.z*kb.z + qa.w*kb.w;
            s10 += qb.x*ka.x + qb.y*ka.y + qb.z*ka.z + qb.w*ka.w;
            s11 += qb.x*kb.x + qb.y*kb.y + qb.z*kb.z + qb.w*kb.w;
        }
        Pt[kj_s     ][qi_s     ] = s00 * SCALE;
        Pt[kj_s + 16][qi_s     ] = s01 * SCALE;
        Pt[kj_s     ][qi_s + 16] = s10 * SCALE;
        Pt[kj_s + 16][qi_s + 16] = s11 * SCALE;
        __syncthreads();

        // ---- online softmax, one thread per query row
        if (t < 32) {
            float tmax = -INFINITY;
#pragma unroll 8
            for (int kj = 0; kj < 32; kj++) tmax = fmaxf(tmax, Pt[kj][t]);
            float mo = m_s[t];
            float mn = fmaxf(mo, tmax);
            float al = __expf(mo - mn);         // exp(-inf)=0 on first tile
            float sum = 0.f;
#pragma unroll 8
            for (int kj = 0; kj < 32; kj++) {
                float pp = __expf(Pt[kj][t] - mn);
                Pt[kj][t] = pp;
                sum += pp;
            }
            l_s[t] = l_s[t] * al + sum;
            m_s[t] = mn;
            al_s[t] = al;
        }
        __syncthreads();

        // ---- O = O*alpha + P·V
        float al0 = al_s[qg*4+0], al1 = al_s[qg*4+1], al2 = al_s[qg*4+2], al3 = al_s[qg*4+3];
#pragma unroll
        for (int j = 0; j < 4; j++) { o[0][j] *= al0; o[1][j] *= al1; o[2][j] *= al2; o[3][j] *= al3; }
#pragma unroll 8
        for (int kj = 0; kj < 32; kj++) {
            float4 p = *(const float4*)&Pt[kj][qg * 4];
            float4 v = *(const float4*)&Vs[kj][dc * 4];
            o[0][0] += p.x*v.x; o[0][1] += p.x*v.y; o[0][2] += p.x*v.z; o[0][3] += p.x*v.w;
            o[1][0] += p.y*v.x; o[1][1] += p.y*v.y; o[1][2] += p.y*v.z; o[1][3] += p.y*v.w;
            o[2][0] += p.z*v.x; o[2][1] += p.z*v.y; o[2][2] += p.z*v.z; o[2][3] += p.z*v.w;
            o[3][0] += p.w*v.x; o[3][1] += p.w*v.y; o[3][2] += p.w*v.z; o[3][3] += p.w*v.w;
        }
        __syncthreads();   // protect Ks/Vs/Pt before next tile's staging
    }

    // finalize: divide by l, write [B,S,D]
#pragma unroll
    for (int i = 0; i < 4; i++) {
        int qi = qg * 4 + i;
        float rinv = 1.f / l_s[qi];
        float4 w = { o[i][0]*rinv, o[i][1]*rinv, o[i][2]*rinv, o[i][3]*rinv };
        *(float4*)(O + ((size_t)(b * SEQ + q0 + qi) * D_MODEL) + h * HD + dc * 4) = w;
    }
}

// ---------------------------------------------------------------------------
extern "C" void kernel_launch(void* const* d_in, const int* in_sizes, int n_in,
                              void* d_out, int out_size, void* d_ws, size_t ws_size,
                              hipStream_t stream)
{
    const float* x  = (const float*)d_in[0];
    const float* Wq = (const float*)d_in[1];
    const float* bq = (const float*)d_in[2];
    const float* Wk = (const float*)d_in[3];
    const float* bk = (const float*)d_in[4];
    const float* Wv = (const float*)d_in[5];
    const float* bv = (const float*)d_in[6];
    const float* Wo = (const float*)d_in[7];
    const float* bo = (const float*)d_in[8];
    float* out = (float*)d_out;

    float* wsf = (float*)d_ws;
    float* Qp = wsf;                    // [B,H,S,HD] rotated Q
    float* Kp = wsf + (size_t)QKV_ELEMS;     // [B,H,S,HD] rotated K
    float* Vp = wsf + (size_t)QKV_ELEMS * 2; // [B,H,S,HD] V
    float* Op = wsf + (size_t)QKV_ELEMS * 3; // [B,S,D] attention output

    // 1) QKV projections (+ reshape to [B,H,S,HD])
    gemm_nt<0><<<dim3(D_MODEL/128, MROWS/128, 3), 256, 0, stream>>>(
        x, Wq, Wk, Wv, bq, bk, bv, Qp, Kp, Vp);

    // 2) RoPE in-place on Q and K
    rope_kernel<<<dim3(2 * BHS_ROWS / 4), 256, 0, stream>>>(Qp, Kp);

    // 3) flash attention -> Op [B,S,D]
    flash_attn<<<dim3(SEQ/32, BATCH*NHEADS), 256, 0, stream>>>(Qp, Kp, Vp, Op);

    // 4) output projection -> d_out
    gemm_nt<1><<<dim3(D_MODEL/128, MROWS/128, 1), 256, 0, stream>>>(
        Op, Wo, Wo, Wo, bo, bo, bo, out, out, out);
}

// Round 2
// 2963.589 us; speedup vs baseline: 1.2049x; 1.2049x over previous
//
#include <hip/hip_runtime.h>
#include <math.h>

// Problem constants
#define D_MODEL 2048
#define NHEADS  16
#define HD      128
#define SEQ     2048
#define BATCH   2
#define SCALE   0.08838834764831845f  // 1/sqrt(128)

typedef __attribute__((ext_vector_type(8))) short short8;   // 8 bf16 = 4 VGPR (MFMA A/B frag)
typedef __attribute__((ext_vector_type(4))) float f32x4;    // MFMA C/D frag

#define MFMA16(a,b,c) __builtin_amdgcn_mfma_f32_16x16x32_bf16((a),(b),(c),0,0,0)

// fp32 -> bf16 RNE, and back
__device__ __forceinline__ unsigned short f2bf(float x){
    unsigned u = __float_as_uint(x);
    return (unsigned short)((u + 0x7FFFu + ((u>>16)&1u)) >> 16);
}
__device__ __forceinline__ float bf2f(unsigned short h){ return __uint_as_float(((unsigned)h)<<16); }

// async global->LDS, 16B per lane. LDS dest must be uniform + lane*16 (it is:
// all call sites use base + (t + 256*i)*16 with full 256-thread blocks).
__device__ __forceinline__ void async16(void* lds, const void* g){
    __builtin_amdgcn_global_load_lds((const __attribute__((address_space(1))) unsigned int*)g,
                                     (__attribute__((address_space(3))) unsigned int*)lds, 16, 0, 0);
}

// ---------------------------------------------------------------------------
// split fp32 -> (hi, lo) bf16 buffers.  n4 = elems/4.
// ---------------------------------------------------------------------------
__global__ __launch_bounds__(256)
void split_w(const float* __restrict__ src, unsigned short* __restrict__ hi,
             unsigned short* __restrict__ lo, int n4)
{
    int i = blockIdx.x*256 + threadIdx.x;
    if (i >= n4) return;
    float4 v = ((const float4*)src)[i];
    ushort4 h, l;
    h.x=f2bf(v.x); l.x=f2bf(v.x-bf2f(h.x));
    h.y=f2bf(v.y); l.y=f2bf(v.y-bf2f(h.y));
    h.z=f2bf(v.z); l.z=f2bf(v.z-bf2f(h.z));
    h.w=f2bf(v.w); l.w=f2bf(v.w-bf2f(h.w));
    ((ushort4*)hi)[i]=h; ((ushort4*)lo)[i]=l;
}

// ---------------------------------------------------------------------------
// QKV projection GEMM, split-bf16 MFMA, fused RoPE epilogue.
// C[m][n] = sum_k x[m][k]*W[n][k] + b[n];  M=4096, N=K=2048.
// x is fp32 (split in-kernel while staging); W pre-split bf16 (hi,lo).
// z=0: RoPE+scale -> Qhi,Qlo [bh][s][d] bf16.  z=1: RoPE -> Khi,Klo.
// z=2: V -> Vt [bh][d][s] bf16 (transposed so PV is a "bt" gemm).
// Block: 256 thr / 4 waves (2x2 over 128x128 tile), per-wave 4x4 MFMA blocks.
// ---------------------------------------------------------------------------
__global__ __launch_bounds__(256,3)
void gemm_qkv(const float* __restrict__ x, const unsigned short* __restrict__ wsplit,
              const float* __restrict__ bq, const float* __restrict__ bk, const float* __restrict__ bv,
              unsigned short* __restrict__ Qhi, unsigned short* __restrict__ Qlo,
              unsigned short* __restrict__ Khi, unsigned short* __restrict__ Klo,
              unsigned short* __restrict__ Vt)
{
    const int z = blockIdx.z;
    const unsigned short* Whi = wsplit + (size_t)z*8388608u;
    const unsigned short* Wlo = Whi + 4194304u;
    const float* bias = (z==0)?bq:((z==1)?bk:bv);

    const int t = threadIdx.x, w = t>>6, lane = t&63;
    const int quad = lane>>4, l15 = lane&15;
    const int mhalf = (w>>1)*64, nhalf = (w&1)*64;
    const int m0 = blockIdx.y*128, n0 = blockIdx.x*128;

    __shared__ __align__(16) unsigned short gsm[16384];   // 32 KiB
    unsigned short* Ahi = gsm;          // [128][32]
    unsigned short* Alo = gsm + 4096;
    unsigned short* Bhi = gsm + 8192;
    unsigned short* Blo = gsm + 12288;

    f32x4 acc[4][4];
#pragma unroll
    for (int i=0;i<4;i++)
#pragma unroll
        for (int j=0;j<4;j++) acc[i][j] = (f32x4){0.f,0.f,0.f,0.f};

    for (int kt=0; kt<2048; kt+=32) {
        float4 xv[4];
#pragma unroll
        for (int i=0;i<4;i++){
            int idx=t+256*i; int row=idx>>3, seg=idx&7;
            xv[i] = *(const float4*)(x + (size_t)(m0+row)*2048 + kt + seg*4);
        }
        __syncthreads();   // prior iter's frag reads done
#pragma unroll
        for (int i=0;i<4;i++){
            int idx=t+256*i; int row=idx>>3, seg=idx&7;
            ushort4 h,l;
            h.x=f2bf(xv[i].x); l.x=f2bf(xv[i].x-bf2f(h.x));
            h.y=f2bf(xv[i].y); l.y=f2bf(xv[i].y-bf2f(h.y));
            h.z=f2bf(xv[i].z); l.z=f2bf(xv[i].z-bf2f(h.z));
            h.w=f2bf(xv[i].w); l.w=f2bf(xv[i].w-bf2f(h.w));
            *(ushort4*)&Ahi[row*32+seg*4] = h;
            *(ushort4*)&Alo[row*32+seg*4] = l;
        }
#pragma unroll
        for (int j=0;j<2;j++){
            int idx=t+256*j; int rw=idx>>2, sg=idx&3;
            async16((char*)&Bhi[rw*32+sg*8], Whi + (size_t)(n0+rw)*2048 + kt + sg*8);
            async16((char*)&Blo[rw*32+sg*8], Wlo + (size_t)(n0+rw)*2048 + kt + sg*8);
        }
        __syncthreads();   // staging complete (vmcnt drained by barrier)

        short8 af_h[4], af_l[4], bf_h[4], bf_l[4];
#pragma unroll
        for (int mi=0;mi<4;mi++){
            int m = mhalf + mi*16 + l15;
            af_h[mi] = *(const short8*)&Ahi[m*32 + quad*8];
            af_l[mi] = *(const short8*)&Alo[m*32 + quad*8];
        }
#pragma unroll
        for (int ni=0;ni<4;ni++){
            int n = nhalf + ni*16 + l15;
            bf_h[ni] = *(const short8*)&Bhi[n*32 + quad*8];
            bf_l[ni] = *(const short8*)&Blo[n*32 + quad*8];
        }
#pragma unroll
        for (int mi=0;mi<4;mi++)
#pragma unroll
            for (int ni=0;ni<4;ni++){
                acc[mi][ni] = MFMA16(af_h[mi], bf_h[ni], acc[mi][ni]);
                acc[mi][ni] = MFMA16(af_l[mi], bf_h[ni], acc[mi][ni]);
                acc[mi][ni] = MFMA16(af_h[mi], bf_l[ni], acc[mi][ni]);
            }
    }
    __syncthreads();   // everyone done with staging LDS before epilogue reuse

    // bias
#pragma unroll
    for (int ni=0;ni<4;ni++){
        float bv_ = bias[n0 + nhalf + ni*16 + l15];
#pragma unroll
        for (int mi=0;mi<4;mi++){
            acc[mi][ni][0]+=bv_; acc[mi][ni][1]+=bv_; acc[mi][ni][2]+=bv_; acc[mi][ni][3]+=bv_;
        }
    }

    const int h = blockIdx.x;   // one head per n-tile (128 == HD)
    if (z == 2) {
        // V: convert + store transposed [bh][d][s]
#pragma unroll
        for (int mi=0;mi<4;mi++)
#pragma unroll
        for (int ni=0;ni<4;ni++)
#pragma unroll
        for (int r=0;r<4;r++){
            int d = nhalf + ni*16 + l15;
            int mg = m0 + mhalf + mi*16 + quad*4 + r;
            int b = mg>>11, s = mg&2047;
            Vt[((size_t)(b*16+h)*128 + d)*2048 + s] = f2bf(acc[mi][ni][r]);
        }
    } else {
        // RoPE: need (d, d+64) pairs -> upper-col waves dump to LDS, lower-col waves combine
        float* xch = (float*)gsm;   // [128][64]
        if (w & 1) {
#pragma unroll
            for (int mi=0;mi<4;mi++)
#pragma unroll
            for (int ni=0;ni<4;ni++)
#pragma unroll
            for (int r=0;r<4;r++)
                xch[(mhalf+mi*16+quad*4+r)*64 + ni*16+l15] = acc[mi][ni][r];
        }
        __syncthreads();
        if (!(w & 1)) {
            unsigned short* OHi = (z==0)?Qhi:Khi;
            unsigned short* OLo = (z==0)?Qlo:Klo;
            const float scl = (z==0)?SCALE:1.0f;
#pragma unroll
            for (int ni=0;ni<4;ni++){
                int d = ni*16 + l15;                       // 0..63 (nhalf==0 here)
                float f = powf(10000.0f, -(float)d*(1.0f/64.0f));
                for (int mi=0;mi<4;mi++)
                for (int r=0;r<4;r++){
                    int ml = mhalf + mi*16 + quad*4 + r;
                    int mg = m0 + ml;
                    int b = mg>>11, s = mg&2047;
                    float sv = (float)s * f;
                    float sn = sinf(sv), cs = cosf(sv);
                    float c_lo = acc[mi][ni][r];
                    float c_hi = xch[ml*64 + d];
                    float o1 = (c_lo*cosf(sn) - c_hi*sinf(sn))*scl;
                    float o2 = (c_hi*cosf(cs) + c_lo*sinf(cs))*scl;
                    size_t base = ((size_t)(b*16+h)*2048 + s)*128;
                    unsigned short h1=f2bf(o1); OHi[base+d]=h1;    OLo[base+d]=f2bf(o1-bf2f(h1));
                    unsigned short h2=f2bf(o2); OHi[base+64+d]=h2; OLo[base+64+d]=f2bf(o2-bf2f(h2));
                }
            }
        }
    }
}

// ---------------------------------------------------------------------------
// MFMA flash attention. Block = 128 queries (4 waves x 32q), K-tiles of 64.
// Q frags in registers (pre-scaled); scores = 3-term split MFMA; online
// softmax with 16-lane shuffle reduce; P -> swizzled per-wave LDS -> PV MFMA.
// Output written as split bf16 (Ohi,Olo) for the final MFMA projection.
// LDS: Khi 16K | Klo 16K | Vt 16K | P 16K  = 65536 B.
// ---------------------------------------------------------------------------
__global__ __launch_bounds__(256,2)
void flash_mfma(const unsigned short* __restrict__ Qhi, const unsigned short* __restrict__ Qlo,
                const unsigned short* __restrict__ Khi, const unsigned short* __restrict__ Klo,
                const unsigned short* __restrict__ Vt,
                unsigned short* __restrict__ Ohi, unsigned short* __restrict__ Olo)
{
    const int t=threadIdx.x, w=t>>6, lane=t&63, quad=lane>>4, l15=lane&15;
    const int bh = blockIdx.y, qt = blockIdx.x;

    __shared__ __align__(16) unsigned short sm[32768];    // 64 KiB exactly
    unsigned short* Ps = sm + 24576 + w*2048;             // per-wave 32x64 bf16, xor-swizzled 16B chunks

    // Q fragments: [hi/lo][mb][kc]
    short8 qf[2][2][4];
    const size_t qrow = (size_t)bh*2048 + qt*128 + w*32;
#pragma unroll
    for (int mb=0;mb<2;mb++){
        size_t r = qrow + mb*16 + l15;
#pragma unroll
        for (int kc=0;kc<4;kc++){
            qf[0][mb][kc] = *(const short8*)(Qhi + r*128 + kc*32 + quad*8);
            qf[1][mb][kc] = *(const short8*)(Qlo + r*128 + kc*32 + quad*8);
        }
    }

    f32x4 O[2][8];
#pragma unroll
    for (int mb=0;mb<2;mb++)
#pragma unroll
        for (int nb=0;nb<8;nb++) O[mb][nb]=(f32x4){0.f,0.f,0.f,0.f};
    float mrow[2][4], lrow[2][4];
#pragma unroll
    for (int mb=0;mb<2;mb++)
#pragma unroll
        for (int r=0;r<4;r++){ mrow[mb][r]=-INFINITY; lrow[mb][r]=0.f; }

    const char* KhiB = (const char*)(Khi + (size_t)bh*2048*128);
    const char* KloB = (const char*)(Klo + (size_t)bh*2048*128);
    const unsigned short* VtB = Vt + (size_t)bh*128*2048;
    char* smb = (char*)sm;

    for (int kt=0; kt<2048; kt+=64) {
#pragma unroll
        for (int i=0;i<4;i++){
            int o16 = t + 256*i;
            async16(smb + o16*16,         KhiB + (size_t)kt*256 + o16*16);
            async16(smb + 16384 + o16*16, KloB + (size_t)kt*256 + o16*16);
            int e = t*8 + i*2048; int d = e>>6, so = e&63;
            async16(smb + 32768 + e*2, VtB + (size_t)d*2048 + kt + so);
        }
        __syncthreads();

        // ---- scores (3-term split)
        f32x4 S[2][4];
#pragma unroll
        for (int mb=0;mb<2;mb++)
#pragma unroll
            for (int nb=0;nb<4;nb++) S[mb][nb]=(f32x4){0.f,0.f,0.f,0.f};
#pragma unroll
        for (int kc=0;kc<4;kc++)
#pragma unroll
        for (int nb=0;nb<4;nb++){
            short8 kh = *(const short8*)&sm[(nb*16+l15)*128 + kc*32 + quad*8];
            short8 kl = *(const short8*)&sm[8192 + (nb*16+l15)*128 + kc*32 + quad*8];
#pragma unroll
            for (int mb=0;mb<2;mb++){
                S[mb][nb] = MFMA16(qf[0][mb][kc], kh, S[mb][nb]);
                S[mb][nb] = MFMA16(qf[1][mb][kc], kh, S[mb][nb]);
                S[mb][nb] = MFMA16(qf[0][mb][kc], kl, S[mb][nb]);
            }
        }

        // ---- online softmax (per mb, rows quad*4+r, 16-lane shuffle reduce)
#pragma unroll
        for (int mb=0;mb<2;mb++){
            float mx[4], al[4], sum[4];
#pragma unroll
            for (int r=0;r<4;r++){
                float v = S[mb][0][r];
                v = fmaxf(v, S[mb][1][r]); v = fmaxf(v, S[mb][2][r]); v = fmaxf(v, S[mb][3][r]);
                mx[r]=v;
            }
#pragma unroll
            for (int d=1;d<16;d<<=1)
#pragma unroll
                for (int r=0;r<4;r++) mx[r] = fmaxf(mx[r], __shfl_xor(mx[r], d));
#pragma unroll
            for (int r=0;r<4;r++){
                float mn = fmaxf(mrow[mb][r], mx[r]);
                al[r] = __expf(mrow[mb][r]-mn);
                mrow[mb][r]=mn; sum[r]=0.f;
            }
#pragma unroll
            for (int nb=0;nb<4;nb++)
#pragma unroll
            for (int r=0;r<4;r++){
                float p = __expf(S[mb][nb][r] - mrow[mb][r]);
                sum[r] += p;
                int q = mb*16 + quad*4 + r;
                int c = nb*16 + l15;
                Ps[q*64 + (((c>>3)^(q&7))<<3) + (c&7)] = f2bf(p);
            }
#pragma unroll
            for (int d=1;d<16;d<<=1)
#pragma unroll
                for (int r=0;r<4;r++) sum[r] += __shfl_xor(sum[r], d);
#pragma unroll
            for (int r=0;r<4;r++) lrow[mb][r] = lrow[mb][r]*al[r] + sum[r];
#pragma unroll
            for (int nb=0;nb<8;nb++){
                O[mb][nb][0]*=al[0]; O[mb][nb][1]*=al[1]; O[mb][nb][2]*=al[2]; O[mb][nb][3]*=al[3];
            }
        }

        // ---- PV  (P is wave-private; in-wave lgkm ordering suffices)
#pragma unroll
        for (int kc2=0;kc2<2;kc2++){
            short8 pf0 = *(const short8*)&Ps[(l15)*64      + (((kc2*4+quad)^(l15&7))<<3)];
            short8 pf1 = *(const short8*)&Ps[(16+l15)*64   + (((kc2*4+quad)^(l15&7))<<3)];
#pragma unroll
            for (int nb=0;nb<8;nb++){
                short8 vf = *(const short8*)&sm[16384 + (nb*16+l15)*64 + kc2*32 + quad*8];
                O[0][nb] = MFMA16(pf0, vf, O[0][nb]);
                O[1][nb] = MFMA16(pf1, vf, O[1][nb]);
            }
        }
        __syncthreads();   // protect K/V/LDS before next staging
    }

    // epilogue: normalize, split to bf16, write [B,S,D]
    const int b = bh>>4, h = bh&15;
#pragma unroll
    for (int mb=0;mb<2;mb++)
#pragma unroll
    for (int nb=0;nb<8;nb++)
#pragma unroll
    for (int r=0;r<4;r++){
        float v = O[mb][nb][r] / lrow[mb][r];
        int qg = qt*128 + w*32 + mb*16 + quad*4 + r;
        size_t base = ((size_t)(b*2048 + qg))*2048 + h*128 + nb*16 + l15;
        unsigned short hh = f2bf(v);
        Ohi[base]=hh; Olo[base]=f2bf(v-bf2f(hh));
    }
}

// ---------------------------------------------------------------------------
// Output projection: out = O·Wo^T + bo, all operands pre-split bf16.
// ---------------------------------------------------------------------------
__global__ __launch_bounds__(256,3)
void gemm_out(const unsigned short* __restrict__ Ahi_g, const unsigned short* __restrict__ Alo_g,
              const unsigned short* __restrict__ Whi_g, const unsigned short* __restrict__ Wlo_g,
              const float* __restrict__ bias, float* __restrict__ out)
{
    const int t = threadIdx.x, w = t>>6, lane = t&63;
    const int quad = lane>>4, l15 = lane&15;
    const int mhalf = (w>>1)*64, nhalf = (w&1)*64;
    const int m0 = blockIdx.y*128, n0 = blockIdx.x*128;

    __shared__ __align__(16) unsigned short gsm[16384];
    unsigned short* Ahi = gsm;
    unsigned short* Alo = gsm + 4096;
    unsigned short* Bhi = gsm + 8192;
    unsigned short* Blo = gsm + 12288;

    f32x4 acc[4][4];
#pragma unroll
    for (int i=0;i<4;i++)
#pragma unroll
        for (int j=0;j<4;j++) acc[i][j] = (f32x4){0.f,0.f,0.f,0.f};

    for (int kt=0; kt<2048; kt+=32) {
        __syncthreads();
#pragma unroll
        for (int j=0;j<2;j++){
            int idx=t+256*j; int rw=idx>>2, sg=idx&3;
            async16((char*)&Ahi[rw*32+sg*8], Ahi_g + (size_t)(m0+rw)*2048 + kt + sg*8);
            async16((char*)&Alo[rw*32+sg*8], Alo_g + (size_t)(m0+rw)*2048 + kt + sg*8);
            async16((char*)&Bhi[rw*32+sg*8], Whi_g + (size_t)(n0+rw)*2048 + kt + sg*8);
            async16((char*)&Blo[rw*32+sg*8], Wlo_g + (size_t)(n0+rw)*2048 + kt + sg*8);
        }
        __syncthreads();

        short8 af_h[4], af_l[4], bf_h[4], bf_l[4];
#pragma unroll
        for (int mi=0;mi<4;mi++){
            int m = mhalf + mi*16 + l15;
            af_h[mi] = *(const short8*)&Ahi[m*32 + quad*8];
            af_l[mi] = *(const short8*)&Alo[m*32 + quad*8];
        }
#pragma unroll
        for (int ni=0;ni<4;ni++){
            int n = nhalf + ni*16 + l15;
            bf_h[ni] = *(const short8*)&Bhi[n*32 + quad*8];
            bf_l[ni] = *(const short8*)&Blo[n*32 + quad*8];
        }
#pragma unroll
        for (int mi=0;mi<4;mi++)
#pragma unroll
            for (int ni=0;ni<4;ni++){
                acc[mi][ni] = MFMA16(af_h[mi], bf_h[ni], acc[mi][ni]);
                acc[mi][ni] = MFMA16(af_l[mi], bf_h[ni], acc[mi][ni]);
                acc[mi][ni] = MFMA16(af_h[mi], bf_l[ni], acc[mi][ni]);
            }
    }

#pragma unroll
    for (int ni=0;ni<4;ni++){
        int n = n0 + nhalf + ni*16 + l15;
        float bv_ = bias[n];
#pragma unroll
        for (int mi=0;mi<4;mi++)
#pragma unroll
        for (int r=0;r<4;r++){
            int m = m0 + mhalf + mi*16 + quad*4 + r;
            out[(size_t)m*2048 + n] = acc[mi][ni][r] + bv_;
        }
    }
}

// ---------------------------------------------------------------------------
extern "C" void kernel_launch(void* const* d_in, const int* in_sizes, int n_in,
                              void* d_out, int out_size, void* d_ws, size_t ws_size,
                              hipStream_t stream)
{
    (void)in_sizes; (void)n_in; (void)out_size; (void)ws_size;
    const float* x  = (const float*)d_in[0];
    const float* Wq = (const float*)d_in[1];
    const float* bq = (const float*)d_in[2];
    const float* Wk = (const float*)d_in[3];
    const float* bk = (const float*)d_in[4];
    const float* Wv = (const float*)d_in[5];
    const float* bv = (const float*)d_in[6];
    const float* Wo = (const float*)d_in[7];
    const float* bo = (const float*)d_in[8];
    float* out = (float*)d_out;

    // workspace layout (ushort units). Region B [0, 25165824): phase1 = Wq/Wk/Wv
    // hi+lo (6 x 4194304); phase2 (after gemm_qkv) = WoHi, WoLo, Ohi, Olo.
    // Region C [25165824, 67108864): Qhi,Qlo,Khi,Klo,Vt (5 x 8388608). 128 MiB total.
    unsigned short* wsB = (unsigned short*)d_ws;
    unsigned short* C0  = wsB + 25165824u;
    unsigned short* Qhi = C0;
    unsigned short* Qlo = C0 + 8388608u;
    unsigned short* Khi = C0 + 16777216u;
    unsigned short* Klo = C0 + 25165824u;
    unsigned short* Vt  = C0 + 33554432u;

    split_w<<<4096,256,0,stream>>>(Wq, wsB,            wsB+4194304u,  1048576);
    split_w<<<4096,256,0,stream>>>(Wk, wsB+8388608u,   wsB+12582912u, 1048576);
    split_w<<<4096,256,0,stream>>>(Wv, wsB+16777216u,  wsB+20971520u, 1048576);

    gemm_qkv<<<dim3(16,32,3),256,0,stream>>>(x, wsB, bq,bk,bv, Qhi,Qlo,Khi,Klo,Vt);

    // Wqkv splits now dead: reuse region B front for Wo split + O split
    unsigned short* WoHi = wsB;
    unsigned short* WoLo = wsB + 4194304u;
    unsigned short* OhiB = wsB + 8388608u;
    unsigned short* OloB = wsB + 16777216u;
    split_w<<<4096,256,0,stream>>>(Wo, WoHi, WoLo, 1048576);

    flash_mfma<<<dim3(16,32),256,0,stream>>>(Qhi,Qlo,Khi,Klo,Vt, OhiB, OloB);

    gemm_out<<<dim3(16,32),256,0,stream>>>(OhiB, OloB, WoHi, WoLo, bo, out);
}

// Round 3
// 769.878 us; speedup vs baseline: 4.6383x; 3.8494x over previous
//
#include <hip/hip_runtime.h>
#include <math.h>

// Problem constants
#define D_MODEL 2048
#define NHEADS  16
#define HD      128
#define SEQ     2048
#define BATCH   2
#define SCALE   0.08838834764831845f  // 1/sqrt(128)

typedef __attribute__((ext_vector_type(8))) short short8;   // 8 bf16 = 4 VGPR (MFMA A/B frag)
typedef __attribute__((ext_vector_type(4))) float f32x4;    // MFMA C/D frag

#define MFMA16(a,b,c) __builtin_amdgcn_mfma_f32_16x16x32_bf16((a),(b),(c),0,0,0)

__device__ __forceinline__ unsigned short f2bf(float x){
    unsigned u = __float_as_uint(x);
    return (unsigned short)((u + 0x7FFFu + ((u>>16)&1u)) >> 16);
}
__device__ __forceinline__ float bf2f(unsigned short h){ return __uint_as_float(((unsigned)h)<<16); }

// async global->LDS, 16B/lane. Per-inst LDS layout is uniform-base + lane*16;
// all call sites keep that shape. Swizzles are applied on the GLOBAL address.
__device__ __forceinline__ void async16(void* lds, const void* g){
    __builtin_amdgcn_global_load_lds((const __attribute__((address_space(1))) unsigned int*)g,
                                     (__attribute__((address_space(3))) unsigned int*)lds, 16, 0, 0);
}

// ---------------------------------------------------------------------------
// split fp32 -> (hi, lo) bf16.  n4 = elems/4.  write_lo=0 -> hi only.
// ---------------------------------------------------------------------------
__global__ __launch_bounds__(256)
void split_w(const float* __restrict__ src, unsigned short* __restrict__ hi,
             unsigned short* __restrict__ lo, int n4, int write_lo)
{
    int i = blockIdx.x*256 + threadIdx.x;
    if (i >= n4) return;
    float4 v = ((const float4*)src)[i];
    ushort4 h, l;
    h.x=f2bf(v.x); l.x=f2bf(v.x-bf2f(h.x));
    h.y=f2bf(v.y); l.y=f2bf(v.y-bf2f(h.y));
    h.z=f2bf(v.z); l.z=f2bf(v.z-bf2f(h.z));
    h.w=f2bf(v.w); l.w=f2bf(v.w-bf2f(h.w));
    ((ushort4*)hi)[i]=h;
    if (write_lo) ((ushort4*)lo)[i]=l;
}

// ---------------------------------------------------------------------------
// RoPE trig table: tab[s*64+d] = {cos(sin(sv)), sin(sin(sv)), cos(cos(sv)),
// sin(cos(sv))}, sv = s * 10000^(-d/64).  2048*64 entries = 2 MiB.
// ---------------------------------------------------------------------------
__global__ __launch_bounds__(256)
void rope_table(float4* __restrict__ tab)
{
    int i = blockIdx.x*256 + threadIdx.x;    // < 131072
    int s = i >> 6, d = i & 63;
    float f = powf(10000.0f, -(float)d * (1.0f/64.0f));
    float sv = (float)s * f;
    float sn = sinf(sv), cs = cosf(sv);
    tab[i] = (float4){cosf(sn), sinf(sn), cosf(cs), sinf(cs)};
}

// ---------------------------------------------------------------------------
// QKV projection, split-bf16 MFMA, fused RoPE (table) epilogue.
// z=0: Q -> Qhi,Qlo (scaled); z=1: K -> Khi,Klo; z=2: V -> Vt [bh][d][s]
// (2-term MFMA for z=2: Vt is rounded to bf16 anyway, Wv lo-term is below
//  that rounding error).  LDS frag layouts xor-swizzled: 16B chunk c of row r
//  stored at chunk c ^ ((r>>1)&3)  (rows are 64B; gives 2-way reads = free).
// ---------------------------------------------------------------------------
__global__ __launch_bounds__(256,2)
void gemm_qkv(const float* __restrict__ x, const unsigned short* __restrict__ wsplit,
              const float* __restrict__ bq, const float* __restrict__ bk, const float* __restrict__ bv,
              const float4* __restrict__ tab,
              unsigned short* __restrict__ Qhi, unsigned short* __restrict__ Qlo,
              unsigned short* __restrict__ Khi, unsigned short* __restrict__ Klo,
              unsigned short* __restrict__ Vt)
{
    const int z = blockIdx.z;
    const unsigned short* Whi = wsplit + (size_t)z*8388608u;
    const unsigned short* Wlo = Whi + 4194304u;
    const float* bias = (z==0)?bq:((z==1)?bk:bv);

    const int t = threadIdx.x, w = t>>6, lane = t&63;
    const int quad = lane>>4, l15 = lane&15;
    const int mhalf = (w>>1)*64, nhalf = (w&1)*64;
    const int m0 = blockIdx.y*128, n0 = blockIdx.x*128;

    __shared__ __align__(16) unsigned short gsm[17408];   // 34 KiB (epilogue needs [128][136])
    unsigned short* Ahi = gsm;          // [128][32] (64B rows, swizzled)
    unsigned short* Alo = gsm + 4096;
    unsigned short* Bhi = gsm + 8192;
    unsigned short* Blo = gsm + 12288;

    f32x4 acc[4][4];
#pragma unroll
    for (int i=0;i<4;i++)
#pragma unroll
        for (int j=0;j<4;j++) acc[i][j] = (f32x4){0.f,0.f,0.f,0.f};

    for (int kt=0; kt<2048; kt+=32) {
        float4 xv[4];
#pragma unroll
        for (int i=0;i<4;i++){
            int idx=t+256*i; int row=idx>>3, seg=idx&7;
            xv[i] = *(const float4*)(x + (size_t)(m0+row)*2048 + kt + seg*4);
        }
        __syncthreads();   // prior iter's frag reads done
#pragma unroll
        for (int i=0;i<4;i++){
            int idx=t+256*i; int row=idx>>3, seg=idx&7;
            int sw = ((seg>>1) ^ ((row>>1)&3))*8 + (seg&1)*4;   // swizzled 8B slot
            ushort4 h,l;
            h.x=f2bf(xv[i].x); l.x=f2bf(xv[i].x-bf2f(h.x));
            h.y=f2bf(xv[i].y); l.y=f2bf(xv[i].y-bf2f(h.y));
            h.z=f2bf(xv[i].z); l.z=f2bf(xv[i].z-bf2f(h.z));
            h.w=f2bf(xv[i].w); l.w=f2bf(xv[i].w-bf2f(h.w));
            *(ushort4*)&Ahi[row*32+sw] = h;
            *(ushort4*)&Alo[row*32+sw] = l;
        }
#pragma unroll
        for (int j=0;j<2;j++){
            int idx=t+256*j; int rw=idx>>2, sg=idx&3;
            int sgp = sg ^ ((rw>>1)&3);                          // global chunk for this slot
            async16((char*)&Bhi[rw*32+sg*8], Whi + (size_t)(n0+rw)*2048 + kt + sgp*8);
            if (z != 2)
                async16((char*)&Blo[rw*32+sg*8], Wlo + (size_t)(n0+rw)*2048 + kt + sgp*8);
        }
        __syncthreads();   // staging complete

        short8 af_h[4], af_l[4], bf_h[4], bf_l[4];
#pragma unroll
        for (int mi=0;mi<4;mi++){
            int m = mhalf + mi*16 + l15;
            int c = (quad ^ ((m>>1)&3))*8;
            af_h[mi] = *(const short8*)&Ahi[m*32 + c];
            af_l[mi] = *(const short8*)&Alo[m*32 + c];
        }
#pragma unroll
        for (int ni=0;ni<4;ni++){
            int n = nhalf + ni*16 + l15;
            int c = (quad ^ ((n>>1)&3))*8;
            bf_h[ni] = *(const short8*)&Bhi[n*32 + c];
            bf_l[ni] = *(const short8*)&Blo[n*32 + c];
        }
#pragma unroll
        for (int mi=0;mi<4;mi++)
#pragma unroll
            for (int ni=0;ni<4;ni++){
                acc[mi][ni] = MFMA16(af_h[mi], bf_h[ni], acc[mi][ni]);
                acc[mi][ni] = MFMA16(af_l[mi], bf_h[ni], acc[mi][ni]);
                if (z != 2) acc[mi][ni] = MFMA16(af_h[mi], bf_l[ni], acc[mi][ni]);
            }
    }
    __syncthreads();   // staging LDS dead; epilogue reuses gsm

    // bias
#pragma unroll
    for (int ni=0;ni<4;ni++){
        float bv_ = bias[n0 + nhalf + ni*16 + l15];
#pragma unroll
        for (int mi=0;mi<4;mi++){
            acc[mi][ni][0]+=bv_; acc[mi][ni][1]+=bv_; acc[mi][ni][2]+=bv_; acc[mi][ni][3]+=bv_;
        }
    }

    const int h = blockIdx.x;   // one head per n-tile (128 == HD)
    if (z == 2) {
        // transpose through LDS -> coalesced 16B Vt stores. [128 d][136] ushort.
#pragma unroll
        for (int mi=0;mi<4;mi++)
#pragma unroll
        for (int ni=0;ni<4;ni++)
#pragma unroll
        for (int r=0;r<4;r++){
            int d = nhalf + ni*16 + l15;
            int ml = mhalf + mi*16 + quad*4 + r;
            gsm[d*136 + ml] = f2bf(acc[mi][ni][r]);
        }
        __syncthreads();
        const int b = m0>>11, s0 = m0&2047;
        unsigned short* vdst = Vt + ((size_t)(b*16+h)*128)*2048;
        const int dr = t>>1, half = (t&1)*64;
#pragma unroll
        for (int j=0;j<8;j++){
            uint4 v = *(const uint4*)&gsm[dr*136 + half + j*8];
            *(uint4*)(vdst + (size_t)dr*2048 + s0 + half + j*8) = v;
        }
    } else {
        // RoPE: (d, d+64) pairs; upper-col waves dump to LDS, lower-col combine
        float* xch = (float*)gsm;   // [128][64]
        if (w & 1) {
#pragma unroll
            for (int mi=0;mi<4;mi++)
#pragma unroll
            for (int ni=0;ni<4;ni++)
#pragma unroll
            for (int r=0;r<4;r++)
                xch[(mhalf+mi*16+quad*4+r)*64 + ni*16+l15] = acc[mi][ni][r];
        }
        __syncthreads();
        if (!(w & 1)) {
            unsigned short* OHi = (z==0)?Qhi:Khi;
            unsigned short* OLo = (z==0)?Qlo:Klo;
            const float scl = (z==0)?SCALE:1.0f;
#pragma unroll
            for (int ni=0;ni<4;ni++){
                int d = ni*16 + l15;                       // 0..63 (nhalf==0 here)
                for (int mi=0;mi<4;mi++)
                for (int r=0;r<4;r++){
                    int ml = mhalf + mi*16 + quad*4 + r;
                    int mg = m0 + ml;
                    int b = mg>>11, s = mg&2047;
                    float4 tv = tab[s*64 + d];
                    float c_lo = acc[mi][ni][r];
                    float c_hi = xch[ml*64 + d];
                    float o1 = (c_lo*tv.x - c_hi*tv.y)*scl;
                    float o2 = (c_hi*tv.z + c_lo*tv.w)*scl;
                    size_t base = ((size_t)(b*16+h)*2048 + s)*128;
                    unsigned short h1=f2bf(o1); OHi[base+d]=h1;    OLo[base+d]=f2bf(o1-bf2f(h1));
                    unsigned short h2=f2bf(o2); OHi[base+64+d]=h2; OLo[base+64+d]=f2bf(o2-bf2f(h2));
                }
            }
        }
    }
}

// ---------------------------------------------------------------------------
// MFMA flash attention. Block = 128 q (4 waves x 32), K-tiles of 64.
// K LDS rows 256B: chunk c of row m stored at c ^ (m&15)  -> 2-way reads.
// V LDS rows 128B: chunk c of row d stored at c ^ (d&7)   -> 2-way reads.
// LDS: Khi 16K | Klo 16K | Vt 16K | P 16K = 64 KiB.
// ---------------------------------------------------------------------------
__global__ __launch_bounds__(256,2)
void flash_mfma(const unsigned short* __restrict__ Qhi, const unsigned short* __restrict__ Qlo,
                const unsigned short* __restrict__ Khi, const unsigned short* __restrict__ Klo,
                const unsigned short* __restrict__ Vt,
                unsigned short* __restrict__ Ohi, unsigned short* __restrict__ Olo)
{
    const int t=threadIdx.x, w=t>>6, lane=t&63, quad=lane>>4, l15=lane&15;
    const int bh = blockIdx.y, qt = blockIdx.x;

    __shared__ __align__(16) unsigned short sm[32768];    // 64 KiB
    unsigned short* Ps = sm + 24576 + w*2048;             // per-wave 32x64, xor-swizzled

    short8 qf[2][2][4];
    const size_t qrow = (size_t)bh*2048 + qt*128 + w*32;
#pragma unroll
    for (int mb=0;mb<2;mb++){
        size_t r = qrow + mb*16 + l15;
#pragma unroll
        for (int kc=0;kc<4;kc++){
            qf[0][mb][kc] = *(const short8*)(Qhi + r*128 + kc*32 + quad*8);
            qf[1][mb][kc] = *(const short8*)(Qlo + r*128 + kc*32 + quad*8);
        }
    }

    f32x4 O[2][8];
#pragma unroll
    for (int mb=0;mb<2;mb++)
#pragma unroll
        for (int nb=0;nb<8;nb++) O[mb][nb]=(f32x4){0.f,0.f,0.f,0.f};
    float mrow[2][4], lrow[2][4];
#pragma unroll
    for (int mb=0;mb<2;mb++)
#pragma unroll
        for (int r=0;r<4;r++){ mrow[mb][r]=-INFINITY; lrow[mb][r]=0.f; }

    const char* KhiB = (const char*)(Khi + (size_t)bh*2048*128);
    const char* KloB = (const char*)(Klo + (size_t)bh*2048*128);
    const unsigned short* VtB = Vt + (size_t)bh*128*2048;
    char* smb = (char*)sm;

    for (int kt=0; kt<2048; kt+=64) {
#pragma unroll
        for (int i=0;i<4;i++){
            int o16 = t + 256*i;
            int krow = o16>>4, kc = o16&15;
            int kcp = kc ^ (krow&15);                       // swizzled global chunk
            async16(smb + i*4096 + t*16,         KhiB + (size_t)kt*256 + krow*256 + kcp*16);
            async16(smb + 16384 + i*4096 + t*16, KloB + (size_t)kt*256 + krow*256 + kcp*16);
            int d = (t>>3) + i*32, c = t&7;
            int cp = c ^ (d&7);
            async16(smb + 32768 + i*4096 + t*16, VtB + (size_t)d*2048 + kt + cp*8);
        }
        __syncthreads();

        // ---- scores (3-term split)
        f32x4 S[2][4];
#pragma unroll
        for (int mb=0;mb<2;mb++)
#pragma unroll
            for (int nb=0;nb<4;nb++) S[mb][nb]=(f32x4){0.f,0.f,0.f,0.f};
#pragma unroll
        for (int kc=0;kc<4;kc++)
#pragma unroll
        for (int nb=0;nb<4;nb++){
            int m = nb*16+l15;
            int c = ((kc*4+quad) ^ (m&15))*8;
            short8 kh = *(const short8*)&sm[m*128 + c];
            short8 kl = *(const short8*)&sm[8192 + m*128 + c];
#pragma unroll
            for (int mb=0;mb<2;mb++){
                S[mb][nb] = MFMA16(qf[0][mb][kc], kh, S[mb][nb]);
                S[mb][nb] = MFMA16(qf[1][mb][kc], kh, S[mb][nb]);
                S[mb][nb] = MFMA16(qf[0][mb][kc], kl, S[mb][nb]);
            }
        }

        // ---- online softmax (rows quad*4+r, 16-lane shuffle reduce)
#pragma unroll
        for (int mb=0;mb<2;mb++){
            float mx[4], al[4], sum[4];
#pragma unroll
            for (int r=0;r<4;r++){
                float v = S[mb][0][r];
                v = fmaxf(v, S[mb][1][r]); v = fmaxf(v, S[mb][2][r]); v = fmaxf(v, S[mb][3][r]);
                mx[r]=v;
            }
#pragma unroll
            for (int d=1;d<16;d<<=1)
#pragma unroll
                for (int r=0;r<4;r++) mx[r] = fmaxf(mx[r], __shfl_xor(mx[r], d));
#pragma unroll
            for (int r=0;r<4;r++){
                float mn = fmaxf(mrow[mb][r], mx[r]);
                al[r] = __expf(mrow[mb][r]-mn);
                mrow[mb][r]=mn; sum[r]=0.f;
            }
#pragma unroll
            for (int nb=0;nb<4;nb++)
#pragma unroll
            for (int r=0;r<4;r++){
                float p = __expf(S[mb][nb][r] - mrow[mb][r]);
                sum[r] += p;
                int q = mb*16 + quad*4 + r;
                int c = nb*16 + l15;
                Ps[q*64 + (((c>>3)^(q&7))<<3) + (c&7)] = f2bf(p);
            }
#pragma unroll
            for (int d=1;d<16;d<<=1)
#pragma unroll
                for (int r=0;r<4;r++) sum[r] += __shfl_xor(sum[r], d);
#pragma unroll
            for (int r=0;r<4;r++) lrow[mb][r] = lrow[mb][r]*al[r] + sum[r];
#pragma unroll
            for (int nb=0;nb<8;nb++){
                O[mb][nb][0]*=al[0]; O[mb][nb][1]*=al[1]; O[mb][nb][2]*=al[2]; O[mb][nb][3]*=al[3];
            }
        }

        // ---- PV
#pragma unroll
        for (int kc2=0;kc2<2;kc2++){
            short8 pf0 = *(const short8*)&Ps[(l15)*64      + (((kc2*4+quad)^(l15&7))<<3)];
            short8 pf1 = *(const short8*)&Ps[(16+l15)*64   + (((kc2*4+quad)^(l15&7))<<3)];
#pragma unroll
            for (int nb=0;nb<8;nb++){
                int d = nb*16+l15;
                int c = ((kc2*4+quad) ^ (d&7))*8;
                short8 vf = *(const short8*)&sm[16384 + d*64 + c];
                O[0][nb] = MFMA16(pf0, vf, O[0][nb]);
                O[1][nb] = MFMA16(pf1, vf, O[1][nb]);
            }
        }
        __syncthreads();
    }

    // epilogue: normalize, split bf16, write [B,S,D]
    const int b = bh>>4, h = bh&15;
#pragma unroll
    for (int mb=0;mb<2;mb++)
#pragma unroll
    for (int nb=0;nb<8;nb++)
#pragma unroll
    for (int r=0;r<4;r++){
        float v = O[mb][nb][r] / lrow[mb][r];
        int qg = qt*128 + w*32 + mb*16 + quad*4 + r;
        size_t base = ((size_t)(b*2048 + qg))*2048 + h*128 + nb*16 + l15;
        unsigned short hh = f2bf(v);
        Ohi[base]=hh; Olo[base]=f2bf(v-bf2f(hh));
    }
}

// ---------------------------------------------------------------------------
// Output projection: out = O·Wo^T + bo, all pre-split bf16, swizzled LDS.
// ---------------------------------------------------------------------------
__global__ __launch_bounds__(256,2)
void gemm_out(const unsigned short* __restrict__ Ahi_g, const unsigned short* __restrict__ Alo_g,
              const unsigned short* __restrict__ Whi_g, const unsigned short* __restrict__ Wlo_g,
              const float* __restrict__ bias, float* __restrict__ out)
{
    const int t = threadIdx.x, w = t>>6, lane = t&63;
    const int quad = lane>>4, l15 = lane&15;
    const int mhalf = (w>>1)*64, nhalf = (w&1)*64;
    const int m0 = blockIdx.y*128, n0 = blockIdx.x*128;

    __shared__ __align__(16) unsigned short gsm[16384];
    unsigned short* Ahi = gsm;
    unsigned short* Alo = gsm + 4096;
    unsigned short* Bhi = gsm + 8192;
    unsigned short* Blo = gsm + 12288;

    f32x4 acc[4][4];
#pragma unroll
    for (int i=0;i<4;i++)
#pragma unroll
        for (int j=0;j<4;j++) acc[i][j] = (f32x4){0.f,0.f,0.f,0.f};

    for (int kt=0; kt<2048; kt+=32) {
        __syncthreads();
#pragma unroll
        for (int j=0;j<2;j++){
            int idx=t+256*j; int rw=idx>>2, sg=idx&3;
            int sgp = sg ^ ((rw>>1)&3);
            async16((char*)&Ahi[rw*32+sg*8], Ahi_g + (size_t)(m0+rw)*2048 + kt + sgp*8);
            async16((char*)&Alo[rw*32+sg*8], Alo_g + (size_t)(m0+rw)*2048 + kt + sgp*8);
            async16((char*)&Bhi[rw*32+sg*8], Whi_g + (size_t)(n0+rw)*2048 + kt + sgp*8);
            async16((char*)&Blo[rw*32+sg*8], Wlo_g + (size_t)(n0+rw)*2048 + kt + sgp*8);
        }
        __syncthreads();

        short8 af_h[4], af_l[4], bf_h[4], bf_l[4];
#pragma unroll
        for (int mi=0;mi<4;mi++){
            int m = mhalf + mi*16 + l15;
            int c = (quad ^ ((m>>1)&3))*8;
            af_h[mi] = *(const short8*)&Ahi[m*32 + c];
            af_l[mi] = *(const short8*)&Alo[m*32 + c];
        }
#pragma unroll
        for (int ni=0;ni<4;ni++){
            int n = nhalf + ni*16 + l15;
            int c = (quad ^ ((n>>1)&3))*8;
            bf_h[ni] = *(const short8*)&Bhi[n*32 + c];
            bf_l[ni] = *(const short8*)&Blo[n*32 + c];
        }
#pragma unroll
        for (int mi=0;mi<4;mi++)
#pragma unroll
            for (int ni=0;ni<4;ni++){
                acc[mi][ni] = MFMA16(af_h[mi], bf_h[ni], acc[mi][ni]);
                acc[mi][ni] = MFMA16(af_l[mi], bf_h[ni], acc[mi][ni]);
                acc[mi][ni] = MFMA16(af_h[mi], bf_l[ni], acc[mi][ni]);
            }
    }

#pragma unroll
    for (int ni=0;ni<4;ni++){
        int n = n0 + nhalf + ni*16 + l15;
        float bv_ = bias[n];
#pragma unroll
        for (int mi=0;mi<4;mi++)
#pragma unroll
        for (int r=0;r<4;r++){
            int m = m0 + mhalf + mi*16 + quad*4 + r;
            out[(size_t)m*2048 + n] = acc[mi][ni][r] + bv_;
        }
    }
}

// ---------------------------------------------------------------------------
extern "C" void kernel_launch(void* const* d_in, const int* in_sizes, int n_in,
                              void* d_out, int out_size, void* d_ws, size_t ws_size,
                              hipStream_t stream)
{
    (void)in_sizes; (void)n_in; (void)out_size; (void)ws_size;
    const float* x  = (const float*)d_in[0];
    const float* Wq = (const float*)d_in[1];
    const float* bq = (const float*)d_in[2];
    const float* Wk = (const float*)d_in[3];
    const float* bk = (const float*)d_in[4];
    const float* Wv = (const float*)d_in[5];
    const float* bv = (const float*)d_in[6];
    const float* Wo = (const float*)d_in[7];
    const float* bo = (const float*)d_in[8];
    float* out = (float*)d_out;

    // ws layout (ushort units), total 127.9 MB < 128 MiB:
    //  A [0, 20971520): Wq hi/lo, Wk hi/lo, Wv hi (5 x 4194304)
    //       -> after gemm_qkv reused: Ohi @0, Olo @8388608
    //  C [20971520, 62914560): Qhi,Qlo,Khi,Klo,Vt (5 x 8388608)
    //       -> after flash reused: WoHi @C0, WoLo @C0+4194304
    //  T [62914560, 63963136): rope table (float4[131072])
    unsigned short* wsB = (unsigned short*)d_ws;
    unsigned short* C0  = wsB + 20971520u;
    unsigned short* Qhi = C0;
    unsigned short* Qlo = C0 + 8388608u;
    unsigned short* Khi = C0 + 16777216u;
    unsigned short* Klo = C0 + 25165824u;
    unsigned short* Vt  = C0 + 33554432u;
    float4* tab = (float4*)(wsB + 62914560u);

    split_w<<<4096,256,0,stream>>>(Wq, wsB,            wsB+4194304u,  1048576, 1);
    split_w<<<4096,256,0,stream>>>(Wk, wsB+8388608u,   wsB+12582912u, 1048576, 1);
    split_w<<<4096,256,0,stream>>>(Wv, wsB+16777216u,  wsB+16777216u, 1048576, 0); // hi only
    rope_table<<<512,256,0,stream>>>(tab);

    gemm_qkv<<<dim3(16,32,3),256,0,stream>>>(x, wsB, bq,bk,bv, tab, Qhi,Qlo,Khi,Klo,Vt);

    unsigned short* Ohi = wsB;
    unsigned short* Olo = wsB + 8388608u;
    flash_mfma<<<dim3(16,32),256,0,stream>>>(Qhi,Qlo,Khi,Klo,Vt, Ohi, Olo);

    unsigned short* WoHi = C0;
    unsigned short* WoLo = C0 + 4194304u;
    split_w<<<4096,256,0,stream>>>(Wo, WoHi, WoLo, 1048576, 1);

    gemm_out<<<dim3(16,32),256,0,stream>>>(Ohi, Olo, WoHi, WoLo, bo, out);
}